// Round 7
// baseline (724.571 us; speedup 1.0000x reference)
//
#include <hip/hip_runtime.h>
#include <stdint.h>

typedef float  f32x4  __attribute__((ext_vector_type(4)));
typedef __bf16 bf16x8 __attribute__((ext_vector_type(8)));
typedef unsigned int   u32;
typedef unsigned short u16;
typedef unsigned long long u64;
typedef u32 u32x4 __attribute__((ext_vector_type(4)));

#define M_TOT 8192
#define N_TOT 4096
#define K_DIN 4096
#define RANK  32
#define KCAT  8320         // 4096 (xq|wq) + 4096 (xb|ws) + 128 (t|lb zero-padded)
#define NT32  260          // KCAT / 32
#define KL32  8288         // (NT32-1)*32

__device__ __forceinline__ u16 f2bf(float f) {
  union { float f; u32 u; } v; v.f = f;
  u32 r = v.u + 0x7fffu + ((v.u >> 16) & 1u);
  return (u16)(r >> 16);
}

// ---- P0: a_sb[r][k] = bf16(lora_a[r][k] * smooth[k])  (32x4096)
__global__ void prep_as_k(const float* __restrict__ la, const float* __restrict__ ss,
                          u16* __restrict__ asb) {
  int i = blockIdx.x * 256 + threadIdx.x;
  f32x4 v = ((const f32x4*)la)[i];
  f32x4 s = ((const f32x4*)ss)[i & 1023];
  f32x4 p = v * s;
  alignas(8) u16 o[4] = { f2bf(p[0]), f2bf(p[1]), f2bf(p[2]), f2bf(p[3]) };
  *(u64*)(asb + 4 * (size_t)i) = *(const u64*)o;
}

// ---- weight cast into B-concat [4096][KCAT] at column offset colofs
__global__ void cvt_w_k(const float* __restrict__ in, u16* __restrict__ Bb, int colofs) {
  int i = blockIdx.x * 256 + threadIdx.x;          // 4M float4s
  f32x4 v = ((const f32x4*)in)[i];
  int r = i >> 10, c = (i & 1023) * 4;
  alignas(8) u16 o[4] = { f2bf(v[0]), f2bf(v[1]), f2bf(v[2]), f2bf(v[3]) };
  *(u64*)(Bb + (size_t)r * KCAT + colofs + c) = *(const u64*)o;
}

// ---- lora_b [4096][32] -> B-concat cols 8192..8223; zero cols 8224..8319
__global__ void cvt_lb_k(const float* __restrict__ in, u16* __restrict__ Bb) {
  int i = blockIdx.x * 256 + threadIdx.x;          // 32768 float4s
  f32x4 v = ((const f32x4*)in)[i];
  int row = i >> 3, c = (i & 7) * 4;
  alignas(8) u16 o[4] = { f2bf(v[0]), f2bf(v[1]), f2bf(v[2]), f2bf(v[3]) };
  u16* rp = Bb + (size_t)row * KCAT;
  *(u64*)(rp + 2 * K_DIN + c) = *(const u64*)o;
  u16* zp = rp + 2 * K_DIN + RANK + (i & 7) * 12;  // 8 threads x 12 cols = 96 zeros
  *(u64*)(zp + 0) = 0; *(u64*)(zp + 4) = 0; *(u64*)(zp + 8) = 0;
}

// ---- P1: smooth+quant -> A-concat cols 0..4095 (xq); raw bf16 -> cols 4096..8191 (xb)
__global__ void prep_x_k(const float* __restrict__ x, const float* __restrict__ ss,
                         u16* __restrict__ Ab) {
  int m = blockIdx.x;
  int t = threadIdx.x;
  const f32x4* xp = (const f32x4*)(x + (size_t)m * K_DIN + t * 16);
  const f32x4* sp = (const f32x4*)(ss + t * 16);
  float xs[16];
  alignas(16) u16 rb[16], qb[16];
  float amax = 0.0f;
  #pragma unroll
  for (int i = 0; i < 4; ++i) {
    f32x4 a = xp[i], s = sp[i];
    #pragma unroll
    for (int j = 0; j < 4; ++j) {
      float xr = a[j];
      float v  = xr * s[j];
      xs[i*4+j] = v;
      amax = fmaxf(amax, fabsf(v));
      rb[i*4+j] = f2bf(xr);
    }
  }
  amax = fmaxf(amax, 1e-12f);
  float scale = amax / 7.0f;                       // IEEE div, matches numpy
  #pragma unroll
  for (int i = 0; i < 16; ++i) {
    float r = rintf(xs[i] / scale);                // RNE, matches jnp.round
    r = fminf(7.0f, fmaxf(-7.0f, r));
    qb[i] = f2bf(r * scale);
  }
  u16* qo = Ab + (size_t)m * KCAT + t * 16;
  ((u32x4*)qo)[0] = ((const u32x4*)qb)[0];
  ((u32x4*)qo)[1] = ((const u32x4*)qb)[1];
  u16* ro = qo + K_DIN;
  ((u32x4*)ro)[0] = ((const u32x4*)rb)[0];
  ((u32x4*)ro)[1] = ((const u32x4*)rb)[1];
}

// ---- P2: t = xb @ a_s^T via MFMA -> A-concat cols 8192..8223; zero 8224..8319
__global__ __launch_bounds__(256)
void lora_t_mfma_k(u16* __restrict__ Ab, const u16* __restrict__ asb) {
  const int wave = threadIdx.x >> 6;
  const int lane = threadIdx.x & 63;
  const int lr = lane & 15, lg = lane >> 4;
  const int m0 = blockIdx.x * 64 + wave * 16;
  f32x4 acc0 = {}, acc1 = {};
  for (int k0 = 0; k0 < K_DIN; k0 += 32) {
    bf16x8 a  = *(const bf16x8*)(Ab + (size_t)(m0 + lr) * KCAT + K_DIN + k0 + lg * 8);
    bf16x8 b0 = *(const bf16x8*)(asb + (size_t)lr        * K_DIN + k0 + lg * 8);
    bf16x8 b1 = *(const bf16x8*)(asb + (size_t)(16 + lr) * K_DIN + k0 + lg * 8);
    acc0 = __builtin_amdgcn_mfma_f32_16x16x32_bf16(a, b0, acc0, 0, 0, 0);
    acc1 = __builtin_amdgcn_mfma_f32_16x16x32_bf16(a, b1, acc1, 0, 0, 0);
  }
  #pragma unroll
  for (int j = 0; j < 4; ++j) {
    const int row = m0 + lg * 4 + j;
    Ab[(size_t)row * KCAT + 2 * K_DIN + lr]      = f2bf(acc0[j]);
    Ab[(size_t)row * KCAT + 2 * K_DIN + 16 + lr] = f2bf(acc1[j]);
  }
  // zero pad cols 8224..8319 for this block's 64 rows (4 threads/row x 24 cols)
  const int zr = blockIdx.x * 64 + (threadIdx.x >> 2);
  u16* zp = Ab + (size_t)zr * KCAT + 2 * K_DIN + RANK + (threadIdx.x & 3) * 24;
  #pragma unroll
  for (int q = 0; q < 6; ++q) *(u64*)(zp + q * 4) = 0;
}

// ====== main GEMM: BM=256 x BN=128, BK=32, 4 waves, 8-phase, 2 blocks/CU ======
__device__ __forceinline__ void gld_lds16(const u16* g, u16* l) {
  __builtin_amdgcn_global_load_lds((const __attribute__((address_space(1))) u32*)g,
                                   (__attribute__((address_space(3))) u32*)l,
                                   16, 0, 0);
}

#define BAR()  __builtin_amdgcn_s_barrier()
#define VMW4() asm volatile("s_waitcnt vmcnt(4)" ::: "memory")
#define BUF1 12288            // elements: A 8192 + B 4096 per buffer

// ds-load A: 4 m-frags (16 rows) of the mh 64-row half; B: 2 n-frags of nh half
#define LDA(bufel, mh) do { _Pragma("unroll")                                        \
  for (int m_ = 0; m_ < 4; ++m_)                                                     \
    Ar[m_] = *(const bf16x8*)(smem + (bufel) + aoff + (mh)*2048 + m_*512);           \
  } while (0)

#define LDB(bufel, nh) do { _Pragma("unroll")                                        \
  for (int n_ = 0; n_ < 2; ++n_)                                                     \
    Br[(nh)*2+n_] = *(const bf16x8*)(smem + (bufel) + boff + (nh)*1024 + n_*512);     \
  } while (0)

// one C-quadrant: 4m x 2n x 1ks = 8 MFMA (T5 setprio)
#define MMQ(mh, nh) do {                                                             \
  __builtin_amdgcn_s_setprio(1);                                                     \
  _Pragma("unroll")                                                                  \
  for (int m_ = 0; m_ < 4; ++m_) { _Pragma("unroll")                                 \
    for (int n_ = 0; n_ < 2; ++n_)                                                   \
      acc[(mh)*4+m_][(nh)*2+n_] = __builtin_amdgcn_mfma_f32_16x16x32_bf16(           \
          Ar[m_], Br[(nh)*2+n_], acc[(mh)*4+m_][(nh)*2+n_], 0, 0, 0);                \
  }                                                                                  \
  __builtin_amdgcn_s_setprio(0);                                                     \
} while (0)

__global__ __launch_bounds__(256, 2)
void gemm2b_k(const u16* __restrict__ Ab, const u16* __restrict__ Bb,
              const float* __restrict__ bias, float* __restrict__ out) {
  __shared__ u16 smem[24576];           // 2 bufs x (A 256x32 + B 128x32) = 48 KiB
  const int tid  = threadIdx.x;
  const int wave = tid >> 6;
  const int lane = tid & 63;
  const int lr = lane & 15, lg = lane >> 4;
  const int wm = wave >> 1, wn = wave & 1;

  // T1: bijective XCD swizzle (1024 % 8 == 0); XCD x -> m in [4x,4x+4), all n
  const int wg  = blockIdx.x;
  const int swz = (wg & 7) * 128 + (wg >> 3);
  const int m0 = (swz >> 5) * 256;
  const int n0 = (swz & 31) * 128;

  // LDS swizzle (64B rows = 4 x 16B blocks): phys_blk = logical_blk ^ ((row>>2)&3)
  // read: logical blk = lg; (row>>2)&3 == (lr>>2)&3 for all frag bases (mult of 16)
  const int kx   = (lg ^ ((lr >> 2) & 3)) * 8;
  const int aoff = (wm * 128 + lr) * 32 + kx;
  const int boff = 8192 + (wn * 64 + lr) * 32 + kx;

  // staging: 64-row call; thread t -> row tid>>2, phys blk tid&3, logical col swizzled
  const int srow = tid >> 2;
  const int scol = ((tid & 3) ^ ((tid >> 4) & 3)) * 8;

  const u16* aRow = Ab + (size_t)(m0 + srow) * KCAT + scol;
  const u16* bRow = Bb + (size_t)(n0 + srow) * KCAT + scol;
  u16* dstA = smem + tid * 8;
  u16* dstB = smem + 8192 + tid * 8;

  bf16x8 Ar[4], Br[4];
  f32x4 acc[8][4] = {};

  // stage one 64-row slab (A: h in 0..3, B: h in 0..1) = 1 gld_lds16 event
  auto stgA = [&](int kof, int h, int bufel) {
    gld_lds16(aRow + (size_t)(h * 64) * KCAT + kof, dstA + bufel + h * 2048);
  };
  auto stgB = [&](int kof, int h, int bufel) {
    gld_lds16(bRow + (size_t)(h * 64) * KCAT + kof, dstB + bufel + h * 2048);
  };

  // prologue: t0 full (6 ev, buf0) + t1 {B0,B1,A0,A2} (4 ev, buf1); gate t0
  stgA(0, 0, 0);  stgA(0, 1, 0);  stgA(0, 2, 0);  stgA(0, 3, 0);
  stgB(0, 0, 0);  stgB(0, 1, 0);
  stgB(32, 0, BUF1); stgB(32, 1, BUF1);
  stgA(32, 0, BUF1); stgA(32, 2, BUF1);
  VMW4();                    // 10 issued, oldest 6 (= t0) landed
  BAR();

  for (int it = 0; it < NT32 / 2; ++it) {
    const int ka = it * 64;                        // tile a k-offset (elements)
    int c2 = ka + 64, c3 = ka + 96;                // tiles a+2, a+3
    if (c2 > KL32) c2 = KL32;                      // tail: junk restage (never read)
    if (c3 > KL32) c3 = KL32;
    // P1: Q00(a) | stage b.A1,A3 -> buf1 (free since prev P7)
    LDA(0, 0); LDB(0, 0);
    stgA(ka + 32, 1, BUF1); stgA(ka + 32, 3, BUF1);
    BAR(); MMQ(0, 0); BAR();
    // P2: Q01(a)
    LDB(0, 1);
    BAR(); MMQ(0, 1); BAR();
    // P3: Q11(a) | stage (a+2).B0,B1 -> buf0 (B free after P2)
    LDA(0, 1);
    stgB(c2, 0, 0); stgB(c2, 1, 0);
    BAR(); MMQ(1, 1); BAR();
    // P4: Q10(a) | stage (a+2).A0,A2 -> buf0 (rows 0-63,128-191 free after P1);
    //             gate: tile b complete (4 younger in flight)
    stgA(c2, 0, 0); stgA(c2, 2, 0);
    BAR(); MMQ(1, 0);
    VMW4();
    BAR();
    // P5: Q00(b) | stage (a+2).A1,A3 (rows 64-127,192-255 free after P3)
    LDA(BUF1, 0); LDB(BUF1, 0);
    stgA(c2, 1, 0); stgA(c2, 3, 0);
    BAR(); MMQ(0, 0); BAR();
    // P6: Q01(b)
    LDB(BUF1, 1);
    BAR(); MMQ(0, 1); BAR();
    // P7: Q11(b) | stage (a+3).B0,B1 -> buf1 (B free after P6)
    LDA(BUF1, 1);
    stgB(c3, 0, BUF1); stgB(c3, 1, BUF1);
    BAR(); MMQ(1, 1); BAR();
    // P8: Q10(b) | stage (a+3).A0,A2 -> buf1 (free after P5); gate: a+2 complete
    stgA(c3, 0, BUF1); stgA(c3, 2, BUF1);
    BAR(); MMQ(1, 0);
    VMW4();
    BAR();
  }

  // epilogue: bias + store (C/D mapping: row=...+lg*4+j, col=...+lr)
  float bv[4];
  #pragma unroll
  for (int n = 0; n < 4; ++n) bv[n] = bias[n0 + wn * 64 + n * 16 + lr];
  #pragma unroll
  for (int m = 0; m < 8; ++m) {
    const int row = m0 + wm * 128 + m * 16 + lg * 4;
    #pragma unroll
    for (int n = 0; n < 4; ++n) {
      const int col = n0 + wn * 64 + n * 16 + lr;
      float* op = out + (size_t)row * N_TOT + col;
      op[0 * (size_t)N_TOT] = acc[m][n][0] + bv[n];
      op[1 * (size_t)N_TOT] = acc[m][n][1] + bv[n];
      op[2 * (size_t)N_TOT] = acc[m][n][2] + bv[n];
      op[3 * (size_t)N_TOT] = acc[m][n][3] + bv[n];
    }
  }
}

extern "C" void kernel_launch(void* const* d_in, const int* in_sizes, int n_in,
                              void* d_out, int out_size, void* d_ws, size_t ws_size,
                              hipStream_t stream) {
  const float* x    = (const float*)d_in[0];
  const float* ss   = (const float*)d_in[1];
  const float* wq   = (const float*)d_in[2];
  const float* la   = (const float*)d_in[3];
  const float* lb   = (const float*)d_in[4];
  const float* wsp  = (const float*)d_in[5];
  const float* bias = (const float*)d_in[6];
  float* out = (float*)d_out;

  uint8_t* w = (uint8_t*)d_ws;
  u16* Ab  = (u16*)w;  w += (size_t)M_TOT * KCAT * 2;    // 130.0 MiB
  u16* Bb  = (u16*)w;  w += (size_t)N_TOT * KCAT * 2;    // 65.0 MiB
  u16* asb = (u16*)w;                                     // 0.25 MiB

  prep_as_k<<<128, 256, 0, stream>>>(la, ss, asb);
  cvt_w_k<<<16384, 256, 0, stream>>>(wq,  Bb, 0);
  cvt_w_k<<<16384, 256, 0, stream>>>(wsp, Bb, K_DIN);
  cvt_lb_k<<<128, 256, 0, stream>>>(lb, Bb);
  prep_x_k<<<M_TOT, 256, 0, stream>>>(x, ss, Ab);
  lora_t_mfma_k<<<M_TOT / 64, 256, 0, stream>>>(Ab, asb);

  gemm2b_k<<<dim3((M_TOT / 256) * (N_TOT / 128)), 256, 0, stream>>>(
      Ab, Bb, bias, out);
}

// Round 9
// 608.885 us; speedup vs baseline: 1.1900x; 1.1900x over previous
//
#include <hip/hip_runtime.h>
#include <stdint.h>

typedef float  f32x4  __attribute__((ext_vector_type(4)));
typedef __bf16 bf16x8 __attribute__((ext_vector_type(8)));
typedef unsigned int   u32;
typedef unsigned short u16;
typedef unsigned long long u64;
typedef u32 u32x4 __attribute__((ext_vector_type(4)));

#define M_TOT 8192
#define N_TOT 4096
#define K_DIN 4096
#define RANK  32
#define KCAT  8320         // 4096 (xq|wq) + 4096 (xb|ws) + 128 (t|lb zero-padded)
#define NTILE 130          // KCAT / 64
#define KLAST 8256         // (NTILE-1)*64

__device__ __forceinline__ u16 f2bf(float f) {
  union { float f; u32 u; } v; v.f = f;
  u32 r = v.u + 0x7fffu + ((v.u >> 16) & 1u);
  return (u16)(r >> 16);
}

// ---- P0: a_sb[r][k] = bf16(lora_a[r][k] * smooth[k])  (32x4096)
__global__ void prep_as_k(const float* __restrict__ la, const float* __restrict__ ss,
                          u16* __restrict__ asb) {
  int i = blockIdx.x * 256 + threadIdx.x;
  f32x4 v = ((const f32x4*)la)[i];
  f32x4 s = ((const f32x4*)ss)[i & 1023];
  f32x4 p = v * s;
  alignas(8) u16 o[4] = { f2bf(p[0]), f2bf(p[1]), f2bf(p[2]), f2bf(p[3]) };
  *(u64*)(asb + 4 * (size_t)i) = *(const u64*)o;
}

// ---- weight cast into B-concat [4096][KCAT] at column offset colofs
__global__ void cvt_w_k(const float* __restrict__ in, u16* __restrict__ Bb, int colofs) {
  int i = blockIdx.x * 256 + threadIdx.x;          // 4M float4s
  f32x4 v = ((const f32x4*)in)[i];
  int r = i >> 10, c = (i & 1023) * 4;
  alignas(8) u16 o[4] = { f2bf(v[0]), f2bf(v[1]), f2bf(v[2]), f2bf(v[3]) };
  *(u64*)(Bb + (size_t)r * KCAT + colofs + c) = *(const u64*)o;
}

// ---- lora_b [4096][32] -> B-concat cols 8192..8223; zero cols 8224..8319
__global__ void cvt_lb_k(const float* __restrict__ in, u16* __restrict__ Bb) {
  int i = blockIdx.x * 256 + threadIdx.x;          // 32768 float4s
  f32x4 v = ((const f32x4*)in)[i];
  int row = i >> 3, c = (i & 7) * 4;
  alignas(8) u16 o[4] = { f2bf(v[0]), f2bf(v[1]), f2bf(v[2]), f2bf(v[3]) };
  u16* rp = Bb + (size_t)row * KCAT;
  *(u64*)(rp + 2 * K_DIN + c) = *(const u64*)o;
  u16* zp = rp + 2 * K_DIN + RANK + (i & 7) * 12;  // 8 threads x 12 cols = 96 zeros
  *(u64*)(zp + 0) = 0; *(u64*)(zp + 4) = 0; *(u64*)(zp + 8) = 0;
}

// ---- P1: smooth+quant -> A-concat cols 0..4095 (xq); raw bf16 -> cols 4096..8191 (xb)
__global__ void prep_x_k(const float* __restrict__ x, const float* __restrict__ ss,
                         u16* __restrict__ Ab) {
  int m = blockIdx.x;
  int t = threadIdx.x;
  const f32x4* xp = (const f32x4*)(x + (size_t)m * K_DIN + t * 16);
  const f32x4* sp = (const f32x4*)(ss + t * 16);
  float xs[16];
  alignas(16) u16 rb[16], qb[16];
  float amax = 0.0f;
  #pragma unroll
  for (int i = 0; i < 4; ++i) {
    f32x4 a = xp[i], s = sp[i];
    #pragma unroll
    for (int j = 0; j < 4; ++j) {
      float xr = a[j];
      float v  = xr * s[j];
      xs[i*4+j] = v;
      amax = fmaxf(amax, fabsf(v));
      rb[i*4+j] = f2bf(xr);
    }
  }
  amax = fmaxf(amax, 1e-12f);
  float scale = amax / 7.0f;                       // IEEE div, matches numpy
  #pragma unroll
  for (int i = 0; i < 16; ++i) {
    float r = rintf(xs[i] / scale);                // RNE, matches jnp.round
    r = fminf(7.0f, fmaxf(-7.0f, r));
    qb[i] = f2bf(r * scale);
  }
  u16* qo = Ab + (size_t)m * KCAT + t * 16;
  ((u32x4*)qo)[0] = ((const u32x4*)qb)[0];
  ((u32x4*)qo)[1] = ((const u32x4*)qb)[1];
  u16* ro = qo + K_DIN;
  ((u32x4*)ro)[0] = ((const u32x4*)rb)[0];
  ((u32x4*)ro)[1] = ((const u32x4*)rb)[1];
}

// ---- P2: t = xb @ a_s^T via MFMA -> A-concat cols 8192..8223; zero 8224..8319
__global__ __launch_bounds__(256)
void lora_t_mfma_k(u16* __restrict__ Ab, const u16* __restrict__ asb) {
  const int wave = threadIdx.x >> 6;
  const int lane = threadIdx.x & 63;
  const int lr = lane & 15, lg = lane >> 4;
  const int m0 = blockIdx.x * 64 + wave * 16;
  f32x4 acc0 = {}, acc1 = {};
  for (int k0 = 0; k0 < K_DIN; k0 += 32) {
    bf16x8 a  = *(const bf16x8*)(Ab + (size_t)(m0 + lr) * KCAT + K_DIN + k0 + lg * 8);
    bf16x8 b0 = *(const bf16x8*)(asb + (size_t)lr        * K_DIN + k0 + lg * 8);
    bf16x8 b1 = *(const bf16x8*)(asb + (size_t)(16 + lr) * K_DIN + k0 + lg * 8);
    acc0 = __builtin_amdgcn_mfma_f32_16x16x32_bf16(a, b0, acc0, 0, 0, 0);
    acc1 = __builtin_amdgcn_mfma_f32_16x16x32_bf16(a, b1, acc1, 0, 0, 0);
  }
  #pragma unroll
  for (int j = 0; j < 4; ++j) {
    const int row = m0 + lg * 4 + j;
    Ab[(size_t)row * KCAT + 2 * K_DIN + lr]      = f2bf(acc0[j]);
    Ab[(size_t)row * KCAT + 2 * K_DIN + 16 + lr] = f2bf(acc1[j]);
  }
  // zero pad cols 8224..8319 for this block's 64 rows (4 threads/row x 24 cols)
  const int zr = blockIdx.x * 64 + (threadIdx.x >> 2);
  u16* zp = Ab + (size_t)zr * KCAT + 2 * K_DIN + RANK + (threadIdx.x & 3) * 24;
  #pragma unroll
  for (int q = 0; q < 6; ++q) *(u64*)(zp + q * 4) = 0;
}

// == main GEMM: 256x256, BK=64, 8-phase; A-frag prefetch INSIDE prior MMQ region ==
__device__ __forceinline__ void gld_lds16(const u16* g, u16* l) {
  __builtin_amdgcn_global_load_lds((const __attribute__((address_space(1))) u32*)g,
                                   (__attribute__((address_space(3))) u32*)l,
                                   16, 0, 0);
}

#define BAR()  __builtin_amdgcn_s_barrier()
#define SB0()  __builtin_amdgcn_sched_barrier(0)
#define VMW6() asm volatile("s_waitcnt vmcnt(6)" ::: "memory")
#define BUF1 32768

// load A-subtile (4 m-frags x 2 ks) into register set AR (R5-exact addresses)
#define LDAS(AR, bufel, mh) do { _Pragma("unroll")                                   \
  for (int m_ = 0; m_ < 4; ++m_) {                                                   \
    AR[m_][0] = *(const bf16x8*)(smem + (bufel) + aoff + ((mh)*4+m_)*1024 + blk0);    \
    AR[m_][1] = *(const bf16x8*)(smem + (bufel) + aoff + ((mh)*4+m_)*1024 + blk1);    \
  } } while (0)

#define LDB(bufel, nh) do { _Pragma("unroll")                                        \
  for (int n_ = 0; n_ < 2; ++n_) {                                                   \
    Br[(nh)*2+n_][0] = *(const bf16x8*)(smem + (bufel) + boff + ((nh)*2+n_)*1024 + blk0); \
    Br[(nh)*2+n_][1] = *(const bf16x8*)(smem + (bufel) + boff + ((nh)*2+n_)*1024 + blk1); \
  } } while (0)

// one C-quadrant: 4m x 2n x 2ks = 16 MFMA from register set AR (T5 setprio)
#define MMQ(AR, mh, nh) do {                                                         \
  __builtin_amdgcn_s_setprio(1);                                                     \
  _Pragma("unroll")                                                                  \
  for (int m_ = 0; m_ < 4; ++m_) { _Pragma("unroll")                                 \
    for (int n_ = 0; n_ < 2; ++n_) {                                                 \
      acc[(mh)*4+m_][(nh)*2+n_] = __builtin_amdgcn_mfma_f32_16x16x32_bf16(           \
          AR[m_][0], Br[(nh)*2+n_][0], acc[(mh)*4+m_][(nh)*2+n_], 0, 0, 0);          \
      acc[(mh)*4+m_][(nh)*2+n_] = __builtin_amdgcn_mfma_f32_16x16x32_bf16(           \
          AR[m_][1], Br[(nh)*2+n_][1], acc[(mh)*4+m_][(nh)*2+n_], 0, 0, 0);          \
    } }                                                                              \
  __builtin_amdgcn_s_setprio(0);                                                     \
} while (0)

__global__ __launch_bounds__(512, 2)
void gemm8_k(const u16* __restrict__ Ab, const u16* __restrict__ Bb,
             const float* __restrict__ bias, float* __restrict__ out) {
  extern __shared__ u16 smem[];           // 2 bufs x (A 16384 + B 16384) elems = 128 KiB
  const int tid  = threadIdx.x;
  const int wave = tid >> 6;
  const int lane = tid & 63;
  const int lr = lane & 15, lg = lane >> 4;
  const int wm = wave >> 2, wn = wave & 3;

  // T1: bijective XCD swizzle (512 % 8 == 0)
  const int wg  = blockIdx.x;
  const int swz = (wg & 7) * 64 + (wg >> 3);
  const int m0 = (swz >> 4) * 256;
  const int n0 = (swz & 15) * 256;

  // ds_read addressing (T2 swizzle, R5-exact: 16B-block cb ^= row&7; row&7 == lr&7)
  const int aoff = wm * 8192 + lr * 64;
  const int boff = 16384 + wn * 4096 + lr * 64;
  const int e7   = lr & 7;
  const int blk0 = ((0 + lg) ^ e7) * 8;
  const int blk1 = ((4 + lg) ^ e7) * 8;

  // staging: thread t covers row tid>>3 (of 64-row issue), source col pre-swizzled
  const int srow = tid >> 3;
  const int scol = ((tid & 7) ^ (srow & 7)) * 8;
  const int woff = wave * 512;

  const u16* aRow = Ab + (size_t)(m0 + srow) * KCAT + scol;
  const u16* bRow = Bb + (size_t)(n0 + srow) * KCAT + scol;
  u16* dstA0 = smem + woff;            // buf0 A h=0 (h=1 at +8192; buf1 at +BUF1)
  u16* dstB0 = smem + 16384 + woff;

  bf16x8 ArA[4][2], ArB[4][2], Br[4][2];
  f32x4 acc[8][4] = {};

  auto stgA = [&](int kof, int h, int bufel) {
    u16* dst = dstA0 + bufel + h * 8192;
    gld_lds16(aRow + (size_t)(h * 128) * KCAT + kof, dst);
    gld_lds16(aRow + (size_t)(h * 128 + 64) * KCAT + kof, dst + 4096);
  };
  auto stgB = [&](int kof, int h, int bufel) {
    u16* dst = dstB0 + bufel + h * 8192;
    gld_lds16(bRow + (size_t)(h * 128) * KCAT + kof, dst);
    gld_lds16(bRow + (size_t)(h * 128 + 64) * KCAT + kof, dst + 4096);
  };

  // prologue: tile0 full (buf0) + t1.B0,B1,A0 (buf1); gate tile0; BAR publishes,
  // THEN preload ArA (race-fix: read only after the publishing barrier)
  stgA(0, 0, 0);     stgA(0, 1, 0);
  stgB(0, 0, 0);     stgB(0, 1, 0);
  stgB(64, 0, BUF1); stgB(64, 1, BUF1);
  stgA(64, 0, BUF1);
  VMW6();
  BAR();
  SB0();
  LDAS(ArA, 0, 0);                    // tile0 half0 (published by BAR above)

  for (int it = 0; it < NTILE / 2; ++it) {
    const int ka = it * 128;
    int c2 = ka + 128, c3 = ka + 192;              // prefetch tiles a+2, a+3
    if (c2 > KLAST) c2 = KLAST;                    // tail: re-stage junk (never read)
    if (c3 > KLAST) c3 = KLAST;
    // P1: Q00(a) uses ArA; load Br01(buf0); stage b.A1 -> buf1
    LDB(0, 0);
    stgA(ka + 64, 1, BUF1);
    BAR(); MMQ(ArA, 0, 0); BAR();
    // P2: Q01(a) uses ArA; load Br23(buf0); PF ArB <- buf0 A-h1 (rides under MMQ)
    LDB(0, 1);
    LDAS(ArB, 0, 1);                 // published since prev-P8's gate+BAR
    BAR(); MMQ(ArA, 0, 1); BAR();
    // P3: Q11(a) uses ArB; stage (a+2).B0,B1
    stgB(c2, 0, 0); stgB(c2, 1, 0);
    BAR(); MMQ(ArB, 1, 1); BAR();
    // P4: Q10(a) uses ArB; stage (a+2).A0; gate tile b; BAR publishes;
    //     PF ArA <- buf1 A-h0 INSIDE MMQ region (overlaps MFMA burst)
    stgA(c2, 0, 0);
    VMW6();                          // tile b complete (oldest 8 of 14)
    BAR();
    SB0();
    LDAS(ArA, BUF1, 0);              // for P5/P6; safe: all waves gated before BAR
    MMQ(ArB, 1, 0); BAR();
    // P5: Q00(b) uses ArA; load Br01(buf1); PF ArB <- buf1 A-h1; stage (a+2).A1
    LDB(BUF1, 0);
    LDAS(ArB, BUF1, 1);              // published by P4's gate+BAR
    stgA(c2, 1, 0);
    BAR(); MMQ(ArA, 0, 0); BAR();
    // P6: Q01(b) uses ArA; load Br23(buf1)
    LDB(BUF1, 1);
    BAR(); MMQ(ArA, 0, 1); BAR();
    // P7: Q11(b) uses ArB; stage (a+3).B0,B1
    stgB(c3, 0, BUF1); stgB(c3, 1, BUF1);
    BAR(); MMQ(ArB, 1, 1); BAR();
    // P8: Q10(b) uses ArB; stage (a+3).A0; gate tile a+2; BAR publishes;
    //     PF ArA <- buf0 A-h0 INSIDE MMQ region
    stgA(c3, 0, BUF1);
    VMW6();                          // tile a+2 complete
    BAR();
    SB0();
    LDAS(ArA, 0, 0);                 // for next-iter P1/P2
    MMQ(ArB, 1, 0); BAR();
  }

  // epilogue: bias + store (C/D mapping: row=...+lg*4+j, col=...+lr)
  float bv[4];
  #pragma unroll
  for (int n = 0; n < 4; ++n) bv[n] = bias[n0 + wn * 64 + n * 16 + lr];
  #pragma unroll
  for (int m = 0; m < 8; ++m) {
    const int row = m0 + wm * 128 + m * 16 + lg * 4;
    #pragma unroll
    for (int n = 0; n < 4; ++n) {
      const int col = n0 + wn * 64 + n * 16 + lr;
      float* op = out + (size_t)row * N_TOT + col;
      op[0 * (size_t)N_TOT] = acc[m][n][0] + bv[n];
      op[1 * (size_t)N_TOT] = acc[m][n][1] + bv[n];
      op[2 * (size_t)N_TOT] = acc[m][n][2] + bv[n];
      op[3 * (size_t)N_TOT] = acc[m][n][3] + bv[n];
    }
  }
}

extern "C" void kernel_launch(void* const* d_in, const int* in_sizes, int n_in,
                              void* d_out, int out_size, void* d_ws, size_t ws_size,
                              hipStream_t stream) {
  const float* x    = (const float*)d_in[0];
  const float* ss   = (const float*)d_in[1];
  const float* wq   = (const float*)d_in[2];
  const float* la   = (const float*)d_in[3];
  const float* lb   = (const float*)d_in[4];
  const float* wsp  = (const float*)d_in[5];
  const float* bias = (const float*)d_in[6];
  float* out = (float*)d_out;

  uint8_t* w = (uint8_t*)d_ws;
  u16* Ab  = (u16*)w;  w += (size_t)M_TOT * KCAT * 2;    // 130.0 MiB
  u16* Bb  = (u16*)w;  w += (size_t)N_TOT * KCAT * 2;    // 65.0 MiB
  u16* asb = (u16*)w;                                     // 0.25 MiB

  prep_as_k<<<128, 256, 0, stream>>>(la, ss, asb);
  cvt_w_k<<<16384, 256, 0, stream>>>(wq,  Bb, 0);
  cvt_w_k<<<16384, 256, 0, stream>>>(wsp, Bb, K_DIN);
  cvt_lb_k<<<128, 256, 0, stream>>>(lb, Bb);
  prep_x_k<<<M_TOT, 256, 0, stream>>>(x, ss, Ab);
  lora_t_mfma_k<<<M_TOT / 64, 256, 0, stream>>>(Ab, asb);

  hipFuncSetAttribute((const void*)gemm8_k,
                      hipFuncAttributeMaxDynamicSharedMemorySize, 131072);
  gemm8_k<<<dim3((N_TOT / 256) * (M_TOT / 256)), 512, 131072, stream>>>(
      Ab, Bb, bias, out);
}

// Round 10
// 608.524 us; speedup vs baseline: 1.1907x; 1.0006x over previous
//
#include <hip/hip_runtime.h>
#include <stdint.h>

typedef float  f32x4  __attribute__((ext_vector_type(4)));
typedef __bf16 bf16x8 __attribute__((ext_vector_type(8)));
typedef unsigned int   u32;
typedef unsigned short u16;
typedef unsigned long long u64;
typedef u32 u32x4 __attribute__((ext_vector_type(4)));

#define M_TOT 8192
#define N_TOT 4096
#define K_DIN 4096
#define RANK  32
#define KCAT  8320         // 4096 (xq|wq) + 4096 (xb|ws) + 128 (t|lb zero-padded)
#define NTILE 130          // KCAT / 64
#define KLAST 8256         // (NTILE-1)*64

__device__ __forceinline__ u16 f2bf(float f) {
  union { float f; u32 u; } v; v.f = f;
  u32 r = v.u + 0x7fffu + ((v.u >> 16) & 1u);
  return (u16)(r >> 16);
}

// ---- consolidated B-side prep: wq/ws casts + lora_b + a_s (one launch)
__global__ void prep_b_k(const float* __restrict__ wq, const float* __restrict__ wsp,
                         const float* __restrict__ lb, const float* __restrict__ la,
                         const float* __restrict__ ss,
                         u16* __restrict__ Bb, u16* __restrict__ asb) {
  const int b = blockIdx.x;
  const int tid = threadIdx.x;
  if (b < 32768) {                       // weight cast into B-concat [4096][KCAT]
    const float* src = (b < 16384) ? wq : wsp;
    const int colofs = (b < 16384) ? 0 : K_DIN;
    const int i = (b & 16383) * 256 + tid;
    f32x4 v = ((const f32x4*)src)[i];
    int r = i >> 10, c = (i & 1023) * 4;
    alignas(8) u16 o[4] = { f2bf(v[0]), f2bf(v[1]), f2bf(v[2]), f2bf(v[3]) };
    *(u64*)(Bb + (size_t)r * KCAT + colofs + c) = *(const u64*)o;
  } else if (b < 32896) {                // lora_b -> cols 8192..8223; zero 8224..8319
    const int i = (b - 32768) * 256 + tid;
    f32x4 v = ((const f32x4*)lb)[i];
    int row = i >> 3, c = (i & 7) * 4;
    alignas(8) u16 o[4] = { f2bf(v[0]), f2bf(v[1]), f2bf(v[2]), f2bf(v[3]) };
    u16* rp = Bb + (size_t)row * KCAT;
    *(u64*)(rp + 2 * K_DIN + c) = *(const u64*)o;
    u16* zp = rp + 2 * K_DIN + RANK + (i & 7) * 12;
    *(u64*)(zp + 0) = 0; *(u64*)(zp + 4) = 0; *(u64*)(zp + 8) = 0;
  } else {                               // a_sb[r][k] = bf16(lora_a * smooth)
    const int i = (b - 32896) * 256 + tid;
    f32x4 v = ((const f32x4*)la)[i];
    f32x4 s = ((const f32x4*)ss)[i & 1023];
    f32x4 p = v * s;
    alignas(8) u16 o[4] = { f2bf(p[0]), f2bf(p[1]), f2bf(p[2]), f2bf(p[3]) };
    *(u64*)(asb + 4 * (size_t)i) = *(const u64*)o;
  }
}

// ---- P1: smooth+quant -> A-concat cols 0..4095 (xq); raw bf16 -> cols 4096..8191 (xb)
__global__ void prep_x_k(const float* __restrict__ x, const float* __restrict__ ss,
                         u16* __restrict__ Ab) {
  int m = blockIdx.x;
  int t = threadIdx.x;
  const f32x4* xp = (const f32x4*)(x + (size_t)m * K_DIN + t * 16);
  const f32x4* sp = (const f32x4*)(ss + t * 16);
  float xs[16];
  alignas(16) u16 rb[16], qb[16];
  float amax = 0.0f;
  #pragma unroll
  for (int i = 0; i < 4; ++i) {
    f32x4 a = xp[i], s = sp[i];
    #pragma unroll
    for (int j = 0; j < 4; ++j) {
      float xr = a[j];
      float v  = xr * s[j];
      xs[i*4+j] = v;
      amax = fmaxf(amax, fabsf(v));
      rb[i*4+j] = f2bf(xr);
    }
  }
  amax = fmaxf(amax, 1e-12f);
  float scale = amax / 7.0f;                       // IEEE div, matches numpy
  #pragma unroll
  for (int i = 0; i < 16; ++i) {
    float r = rintf(xs[i] / scale);                // RNE, matches jnp.round
    r = fminf(7.0f, fmaxf(-7.0f, r));
    qb[i] = f2bf(r * scale);
  }
  u16* qo = Ab + (size_t)m * KCAT + t * 16;
  ((u32x4*)qo)[0] = ((const u32x4*)qb)[0];
  ((u32x4*)qo)[1] = ((const u32x4*)qb)[1];
  u16* ro = qo + K_DIN;
  ((u32x4*)ro)[0] = ((const u32x4*)rb)[0];
  ((u32x4*)ro)[1] = ((const u32x4*)rb)[1];
}

// ---- P2: t = xb @ a_s^T via MFMA -> A-concat cols 8192..8223; zero 8224..8319
__global__ __launch_bounds__(256)
void lora_t_mfma_k(u16* __restrict__ Ab, const u16* __restrict__ asb) {
  const int wave = threadIdx.x >> 6;
  const int lane = threadIdx.x & 63;
  const int lr = lane & 15, lg = lane >> 4;
  const int m0 = blockIdx.x * 64 + wave * 16;
  f32x4 acc0 = {}, acc1 = {};
  for (int k0 = 0; k0 < K_DIN; k0 += 32) {
    bf16x8 a  = *(const bf16x8*)(Ab + (size_t)(m0 + lr) * KCAT + K_DIN + k0 + lg * 8);
    bf16x8 b0 = *(const bf16x8*)(asb + (size_t)lr        * K_DIN + k0 + lg * 8);
    bf16x8 b1 = *(const bf16x8*)(asb + (size_t)(16 + lr) * K_DIN + k0 + lg * 8);
    acc0 = __builtin_amdgcn_mfma_f32_16x16x32_bf16(a, b0, acc0, 0, 0, 0);
    acc1 = __builtin_amdgcn_mfma_f32_16x16x32_bf16(a, b1, acc1, 0, 0, 0);
  }
  #pragma unroll
  for (int j = 0; j < 4; ++j) {
    const int row = m0 + lg * 4 + j;
    Ab[(size_t)row * KCAT + 2 * K_DIN + lr]      = f2bf(acc0[j]);
    Ab[(size_t)row * KCAT + 2 * K_DIN + 16 + lr] = f2bf(acc1[j]);
  }
  // zero pad cols 8224..8319 for this block's 64 rows (4 threads/row x 24 cols)
  const int zr = blockIdx.x * 64 + (threadIdx.x >> 2);
  u16* zp = Ab + (size_t)zr * KCAT + 2 * K_DIN + RANK + (threadIdx.x & 3) * 24;
  #pragma unroll
  for (int q = 0; q < 6; ++q) *(u64*)(zp + q * 4) = 0;
}

// == main GEMM: 256x256, BK=64, 4 windows/iter (32-MFMA clusters, 8 barriers/iter) ==
// Dataflow, staging-event order, and both vmcnt(6) gate positions are byte-identical
// to the verified R5 ledger; only quadrant pairs are merged per barrier window.
__device__ __forceinline__ void gld_lds16(const u16* g, u16* l) {
  __builtin_amdgcn_global_load_lds((const __attribute__((address_space(1))) u32*)g,
                                   (__attribute__((address_space(3))) u32*)l,
                                   16, 0, 0);
}

#define BAR()  __builtin_amdgcn_s_barrier()
#define VMW6() asm volatile("s_waitcnt vmcnt(6)" ::: "memory")
#define BUF1 32768

// ds-load A-subtile (4 m-frags x 2 ks) / B-subtile (2 n-frags x 2 ks)
#define LDA(bufel, mh) do { _Pragma("unroll")                                        \
  for (int m_ = 0; m_ < 4; ++m_) {                                                   \
    Ar[m_][0] = *(const bf16x8*)(smem + (bufel) + aoff + ((mh)*4+m_)*1024 + blk0);    \
    Ar[m_][1] = *(const bf16x8*)(smem + (bufel) + aoff + ((mh)*4+m_)*1024 + blk1);    \
  } } while (0)

#define LDB(bufel, nh) do { _Pragma("unroll")                                        \
  for (int n_ = 0; n_ < 2; ++n_) {                                                   \
    Br[(nh)*2+n_][0] = *(const bf16x8*)(smem + (bufel) + boff + ((nh)*2+n_)*1024 + blk0); \
    Br[(nh)*2+n_][1] = *(const bf16x8*)(smem + (bufel) + boff + ((nh)*2+n_)*1024 + blk1); \
  } } while (0)

// one C half (m-half mh x all 4 n-frags x 2 ks) = 32 MFMA, setprio-wrapped (T5)
#define MMQ2(mh) do {                                                                \
  __builtin_amdgcn_s_setprio(1);                                                     \
  _Pragma("unroll")                                                                  \
  for (int m_ = 0; m_ < 4; ++m_) { _Pragma("unroll")                                 \
    for (int n_ = 0; n_ < 4; ++n_) {                                                 \
      acc[(mh)*4+m_][n_] = __builtin_amdgcn_mfma_f32_16x16x32_bf16(                  \
          Ar[m_][0], Br[n_][0], acc[(mh)*4+m_][n_], 0, 0, 0);                        \
      acc[(mh)*4+m_][n_] = __builtin_amdgcn_mfma_f32_16x16x32_bf16(                  \
          Ar[m_][1], Br[n_][1], acc[(mh)*4+m_][n_], 0, 0, 0);                        \
    } }                                                                              \
  __builtin_amdgcn_s_setprio(0);                                                     \
} while (0)

__global__ __launch_bounds__(512, 2)
void gemm8_k(const u16* __restrict__ Ab, const u16* __restrict__ Bb,
             const float* __restrict__ bias, float* __restrict__ out) {
  extern __shared__ u16 smem[];           // 2 bufs x (A 16384 + B 16384) elems = 128 KiB
  const int tid  = threadIdx.x;
  const int wave = tid >> 6;
  const int lane = tid & 63;
  const int lr = lane & 15, lg = lane >> 4;
  const int wm = wave >> 2, wn = wave & 3;

  // T1: bijective XCD swizzle (512 % 8 == 0)
  const int wg  = blockIdx.x;
  const int swz = (wg & 7) * 64 + (wg >> 3);
  const int m0 = (swz >> 4) * 256;
  const int n0 = (swz & 15) * 256;

  // ds_read addressing (T2 swizzle, R5-exact: 16B-block cb ^= row&7; row&7 == lr&7)
  const int aoff = wm * 8192 + lr * 64;
  const int boff = 16384 + wn * 4096 + lr * 64;
  const int e7   = lr & 7;
  const int blk0 = ((0 + lg) ^ e7) * 8;
  const int blk1 = ((4 + lg) ^ e7) * 8;

  // staging: thread t covers row tid>>3 (of 64-row issue), source col pre-swizzled
  const int srow = tid >> 3;
  const int scol = ((tid & 7) ^ (srow & 7)) * 8;
  const int woff = wave * 512;

  const u16* aRow = Ab + (size_t)(m0 + srow) * KCAT + scol;
  const u16* bRow = Bb + (size_t)(n0 + srow) * KCAT + scol;
  u16* dstA0 = smem + woff;            // buf0 A h=0 (h=1 at +8192; buf1 at +BUF1)
  u16* dstB0 = smem + 16384 + woff;

  bf16x8 Ar[4][2], Br[4][2];
  f32x4 acc[8][4] = {};

  auto stgA = [&](int kof, int h, int bufel) {
    u16* dst = dstA0 + bufel + h * 8192;
    gld_lds16(aRow + (size_t)(h * 128) * KCAT + kof, dst);
    gld_lds16(aRow + (size_t)(h * 128 + 64) * KCAT + kof, dst + 4096);
  };
  auto stgB = [&](int kof, int h, int bufel) {
    u16* dst = dstB0 + bufel + h * 8192;
    gld_lds16(bRow + (size_t)(h * 128) * KCAT + kof, dst);
    gld_lds16(bRow + (size_t)(h * 128 + 64) * KCAT + kof, dst + 4096);
  };

  // prologue (R5-exact): tile0 full (buf0) + t1.B0,B1,A0 (buf1); gate tile0
  stgA(0, 0, 0);     stgA(0, 1, 0);
  stgB(0, 0, 0);     stgB(0, 1, 0);
  stgB(64, 0, BUF1); stgB(64, 1, BUF1);
  stgA(64, 0, BUF1);
  VMW6();                               // 14 loads issued, oldest 8 (= tile0) landed
  BAR();

  for (int it = 0; it < NTILE / 2; ++it) {
    const int ka = it * 128;
    int c2 = ka + 128, c3 = ka + 192;              // prefetch tiles a+2, a+3
    if (c2 > KLAST) c2 = KLAST;                    // tail: re-stage junk (never read)
    if (c3 > KLAST) c3 = KLAST;
    // W1: reads tile a A-h0 + B(h0,h1); stage e1 = b.A1 -> buf1
    LDA(0, 0); LDB(0, 0); LDB(0, 1);
    stgA(ka + 64, 1, BUF1);
    BAR(); MMQ2(0); BAR();
    // W2: reads tile a A-h1; stages e2,e3,e4 = (a+2).B0,B1,A0 -> buf0; gate tile b
    LDA(0, 1);
    stgB(c2, 0, 0); stgB(c2, 1, 0); stgA(c2, 0, 0);
    BAR(); MMQ2(1);
    VMW6();                            // oldest 8 = tile b complete; 6 in flight
    BAR();
    // W3: reads tile b A-h0 + B(h0,h1); stage e5 = (a+2).A1 -> buf0
    LDA(BUF1, 0); LDB(BUF1, 0); LDB(BUF1, 1);
    stgA(c2, 1, 0);
    BAR(); MMQ2(0); BAR();
    // W4: reads tile b A-h1; stages e6,e7,e8 = (a+3).B0,B1,A0 -> buf1; gate a+2
    LDA(BUF1, 1);
    stgB(c3, 0, BUF1); stgB(c3, 1, BUF1); stgA(c3, 0, BUF1);
    BAR(); MMQ2(1);
    VMW6();                            // oldest 8 = tile a+2 complete; 6 in flight
    BAR();
  }

  // epilogue: bias + store (C/D mapping: row=...+lg*4+j, col=...+lr)
  float bv[4];
  #pragma unroll
  for (int n = 0; n < 4; ++n) bv[n] = bias[n0 + wn * 64 + n * 16 + lr];
  #pragma unroll
  for (int m = 0; m < 8; ++m) {
    const int row = m0 + wm * 128 + m * 16 + lg * 4;
    #pragma unroll
    for (int n = 0; n < 4; ++n) {
      const int col = n0 + wn * 64 + n * 16 + lr;
      float* op = out + (size_t)row * N_TOT + col;
      op[0 * (size_t)N_TOT] = acc[m][n][0] + bv[n];
      op[1 * (size_t)N_TOT] = acc[m][n][1] + bv[n];
      op[2 * (size_t)N_TOT] = acc[m][n][2] + bv[n];
      op[3 * (size_t)N_TOT] = acc[m][n][3] + bv[n];
    }
  }
}

extern "C" void kernel_launch(void* const* d_in, const int* in_sizes, int n_in,
                              void* d_out, int out_size, void* d_ws, size_t ws_size,
                              hipStream_t stream) {
  const float* x    = (const float*)d_in[0];
  const float* ss   = (const float*)d_in[1];
  const float* wq   = (const float*)d_in[2];
  const float* la   = (const float*)d_in[3];
  const float* lb   = (const float*)d_in[4];
  const float* wsp  = (const float*)d_in[5];
  const float* bias = (const float*)d_in[6];
  float* out = (float*)d_out;

  uint8_t* w = (uint8_t*)d_ws;
  u16* Ab  = (u16*)w;  w += (size_t)M_TOT * KCAT * 2;    // 130.0 MiB
  u16* Bb  = (u16*)w;  w += (size_t)N_TOT * KCAT * 2;    // 65.0 MiB
  u16* asb = (u16*)w;                                     // 0.25 MiB

  prep_b_k<<<33024, 256, 0, stream>>>(wq, wsp, lb, la, ss, Bb, asb);
  prep_x_k<<<M_TOT, 256, 0, stream>>>(x, ss, Ab);
  lora_t_mfma_k<<<M_TOT / 64, 256, 0, stream>>>(Ab, asb);

  hipFuncSetAttribute((const void*)gemm8_k,
                      hipFuncAttributeMaxDynamicSharedMemorySize, 131072);
  gemm8_k<<<dim3((N_TOT / 256) * (M_TOT / 256)), 512, 131072, stream>>>(
      Ab, Bb, bias, out);
}

// Round 11
// 586.211 us; speedup vs baseline: 1.2360x; 1.0381x over previous
//
#include <hip/hip_runtime.h>
#include <stdint.h>

typedef float  f32x4  __attribute__((ext_vector_type(4)));
typedef __bf16 bf16x8 __attribute__((ext_vector_type(8)));
typedef unsigned int   u32;
typedef unsigned short u16;
typedef unsigned long long u64;
typedef u32 u32x4 __attribute__((ext_vector_type(4)));

#define M_TOT 8192
#define N_TOT 4096
#define K_DIN 4096
#define RANK  32
#define KCAT  8320         // 4096 (xq|wq) + 4096 (xb|ws) + 128 (t|lb zero-padded)
#define NTILE 130          // KCAT / 64
#define KLAST 8256         // (NTILE-1)*64

__device__ __forceinline__ u16 f2bf(float f) {
  union { float f; u32 u; } v; v.f = f;
  u32 r = v.u + 0x7fffu + ((v.u >> 16) & 1u);
  return (u16)(r >> 16);
}

// ---- consolidated B-side prep: wq/ws casts + lora_b + a_s (one launch, R10-exact)
__global__ void prep_b_k(const float* __restrict__ wq, const float* __restrict__ wsp,
                         const float* __restrict__ lb, const float* __restrict__ la,
                         const float* __restrict__ ss,
                         u16* __restrict__ Bb, u16* __restrict__ asb) {
  const int b = blockIdx.x;
  const int tid = threadIdx.x;
  if (b < 32768) {                       // weight cast into B-concat [4096][KCAT]
    const float* src = (b < 16384) ? wq : wsp;
    const int colofs = (b < 16384) ? 0 : K_DIN;
    const int i = (b & 16383) * 256 + tid;
    f32x4 v = ((const f32x4*)src)[i];
    int r = i >> 10, c = (i & 1023) * 4;
    alignas(8) u16 o[4] = { f2bf(v[0]), f2bf(v[1]), f2bf(v[2]), f2bf(v[3]) };
    *(u64*)(Bb + (size_t)r * KCAT + colofs + c) = *(const u64*)o;
  } else if (b < 32896) {                // lora_b -> cols 8192..8223; zero 8224..8319
    const int i = (b - 32768) * 256 + tid;
    f32x4 v = ((const f32x4*)lb)[i];
    int row = i >> 3, c = (i & 7) * 4;
    alignas(8) u16 o[4] = { f2bf(v[0]), f2bf(v[1]), f2bf(v[2]), f2bf(v[3]) };
    u16* rp = Bb + (size_t)row * KCAT;
    *(u64*)(rp + 2 * K_DIN + c) = *(const u64*)o;
    u16* zp = rp + 2 * K_DIN + RANK + (i & 7) * 12;
    *(u64*)(zp + 0) = 0; *(u64*)(zp + 4) = 0; *(u64*)(zp + 8) = 0;
  } else {                               // a_sb[r][k] = bf16(lora_a * smooth)
    const int i = (b - 32896) * 256 + tid;
    f32x4 v = ((const f32x4*)la)[i];
    f32x4 s = ((const f32x4*)ss)[i & 1023];
    f32x4 p = v * s;
    alignas(8) u16 o[4] = { f2bf(p[0]), f2bf(p[1]), f2bf(p[2]), f2bf(p[3]) };
    *(u64*)(asb + 4 * (size_t)i) = *(const u64*)o;
  }
}

// ---- P1: smooth+quant -> A-concat cols 0..4095 (xq); raw bf16 -> cols 4096..8191 (xb)
__global__ void prep_x_k(const float* __restrict__ x, const float* __restrict__ ss,
                         u16* __restrict__ Ab) {
  int m = blockIdx.x;
  int t = threadIdx.x;
  const f32x4* xp = (const f32x4*)(x + (size_t)m * K_DIN + t * 16);
  const f32x4* sp = (const f32x4*)(ss + t * 16);
  float xs[16];
  alignas(16) u16 rb[16], qb[16];
  float amax = 0.0f;
  #pragma unroll
  for (int i = 0; i < 4; ++i) {
    f32x4 a = xp[i], s = sp[i];
    #pragma unroll
    for (int j = 0; j < 4; ++j) {
      float xr = a[j];
      float v  = xr * s[j];
      xs[i*4+j] = v;
      amax = fmaxf(amax, fabsf(v));
      rb[i*4+j] = f2bf(xr);
    }
  }
  amax = fmaxf(amax, 1e-12f);
  float scale = amax / 7.0f;                       // IEEE div, matches numpy
  #pragma unroll
  for (int i = 0; i < 16; ++i) {
    float r = rintf(xs[i] / scale);                // RNE, matches jnp.round
    r = fminf(7.0f, fmaxf(-7.0f, r));
    qb[i] = f2bf(r * scale);
  }
  u16* qo = Ab + (size_t)m * KCAT + t * 16;
  ((u32x4*)qo)[0] = ((const u32x4*)qb)[0];
  ((u32x4*)qo)[1] = ((const u32x4*)qb)[1];
  u16* ro = qo + K_DIN;
  ((u32x4*)ro)[0] = ((const u32x4*)rb)[0];
  ((u32x4*)ro)[1] = ((const u32x4*)rb)[1];
}

// ---- P2: t = xb @ a_s^T via MFMA -> A-concat cols 8192..8223; zero 8224..8319
__global__ __launch_bounds__(256)
void lora_t_mfma_k(u16* __restrict__ Ab, const u16* __restrict__ asb) {
  const int wave = threadIdx.x >> 6;
  const int lane = threadIdx.x & 63;
  const int lr = lane & 15, lg = lane >> 4;
  const int m0 = blockIdx.x * 64 + wave * 16;
  f32x4 acc0 = {}, acc1 = {};
  for (int k0 = 0; k0 < K_DIN; k0 += 32) {
    bf16x8 a  = *(const bf16x8*)(Ab + (size_t)(m0 + lr) * KCAT + K_DIN + k0 + lg * 8);
    bf16x8 b0 = *(const bf16x8*)(asb + (size_t)lr        * K_DIN + k0 + lg * 8);
    bf16x8 b1 = *(const bf16x8*)(asb + (size_t)(16 + lr) * K_DIN + k0 + lg * 8);
    acc0 = __builtin_amdgcn_mfma_f32_16x16x32_bf16(a, b0, acc0, 0, 0, 0);
    acc1 = __builtin_amdgcn_mfma_f32_16x16x32_bf16(a, b1, acc1, 0, 0, 0);
  }
  #pragma unroll
  for (int j = 0; j < 4; ++j) {
    const int row = m0 + lg * 4 + j;
    Ab[(size_t)row * KCAT + 2 * K_DIN + lr]      = f2bf(acc0[j]);
    Ab[(size_t)row * KCAT + 2 * K_DIN + 16 + lr] = f2bf(acc1[j]);
  }
  // zero pad cols 8224..8319 for this block's 64 rows (4 threads/row x 24 cols)
  const int zr = blockIdx.x * 64 + (threadIdx.x >> 2);
  u16* zp = Ab + (size_t)zr * KCAT + 2 * K_DIN + RANK + (threadIdx.x & 3) * 24;
  #pragma unroll
  for (int q = 0; q < 6; ++q) *(u64*)(zp + q * 4) = 0;
}

// ========== main GEMM: R5-exact (measured 476 us, MfmaUtil 53%, 0 conflicts) =======
__device__ __forceinline__ void gld_lds16(const u16* g, u16* l) {
  __builtin_amdgcn_global_load_lds((const __attribute__((address_space(1))) u32*)g,
                                   (__attribute__((address_space(3))) u32*)l,
                                   16, 0, 0);
}

#define BAR()  __builtin_amdgcn_s_barrier()
#define VMW6() asm volatile("s_waitcnt vmcnt(6)" ::: "memory")
#define BUF1 32768

// ds-load A-subtile (4 m-frags x 2 ks) / B-subtile (2 n-frags x 2 ks)
#define LDA(bufel, mh) do { _Pragma("unroll")                                        \
  for (int m_ = 0; m_ < 4; ++m_) {                                                   \
    Ar[m_][0] = *(const bf16x8*)(smem + (bufel) + aoff + ((mh)*4+m_)*1024 + blk0);    \
    Ar[m_][1] = *(const bf16x8*)(smem + (bufel) + aoff + ((mh)*4+m_)*1024 + blk1);    \
  } } while (0)

#define LDB(bufel, nh) do { _Pragma("unroll")                                        \
  for (int n_ = 0; n_ < 2; ++n_) {                                                   \
    Br[(nh)*2+n_][0] = *(const bf16x8*)(smem + (bufel) + boff + ((nh)*2+n_)*1024 + blk0); \
    Br[(nh)*2+n_][1] = *(const bf16x8*)(smem + (bufel) + boff + ((nh)*2+n_)*1024 + blk1); \
  } } while (0)

// one C-quadrant: 4m x 2n x 2ks = 16 MFMA, setprio-wrapped (T5)
#define MMQ(mh, nh) do {                                                             \
  __builtin_amdgcn_s_setprio(1);                                                     \
  _Pragma("unroll")                                                                  \
  for (int m_ = 0; m_ < 4; ++m_) { _Pragma("unroll")                                 \
    for (int n_ = 0; n_ < 2; ++n_) {                                                 \
      acc[(mh)*4+m_][(nh)*2+n_] = __builtin_amdgcn_mfma_f32_16x16x32_bf16(           \
          Ar[m_][0], Br[(nh)*2+n_][0], acc[(mh)*4+m_][(nh)*2+n_], 0, 0, 0);          \
      acc[(mh)*4+m_][(nh)*2+n_] = __builtin_amdgcn_mfma_f32_16x16x32_bf16(           \
          Ar[m_][1], Br[(nh)*2+n_][1], acc[(mh)*4+m_][(nh)*2+n_], 0, 0, 0);          \
    } }                                                                              \
  __builtin_amdgcn_s_setprio(0);                                                     \
} while (0)

__global__ __launch_bounds__(512, 2)
void gemm8_k(const u16* __restrict__ Ab, const u16* __restrict__ Bb,
             const float* __restrict__ bias, float* __restrict__ out) {
  extern __shared__ u16 smem[];           // 2 bufs x (A 16384 + B 16384) elems = 128 KiB
  const int tid  = threadIdx.x;
  const int wave = tid >> 6;
  const int lane = tid & 63;
  const int lr = lane & 15, lg = lane >> 4;
  const int wm = wave >> 2, wn = wave & 3;

  // T1: bijective XCD swizzle (512 % 8 == 0)
  const int wg  = blockIdx.x;
  const int swz = (wg & 7) * 64 + (wg >> 3);
  const int m0 = (swz >> 4) * 256;
  const int n0 = (swz & 15) * 256;

  // ds_read addressing (T2 swizzle: 16B-block cb ^= row&7; row&7 == lr&7)
  const int aoff = wm * 8192 + lr * 64;
  const int boff = 16384 + wn * 4096 + lr * 64;
  const int e7   = lr & 7;
  const int blk0 = ((0 + lg) ^ e7) * 8;
  const int blk1 = ((4 + lg) ^ e7) * 8;

  // staging: thread t covers row tid>>3 (of 64-row issue), source col pre-swizzled
  const int srow = tid >> 3;
  const int scol = ((tid & 7) ^ (srow & 7)) * 8;
  const int woff = wave * 512;

  const u16* aRow = Ab + (size_t)(m0 + srow) * KCAT + scol;
  const u16* bRow = Bb + (size_t)(n0 + srow) * KCAT + scol;
  u16* dstA0 = smem + woff;            // buf0 A h=0 (h=1 at +8192; buf1 at +BUF1)
  u16* dstB0 = smem + 16384 + woff;

  bf16x8 Ar[4][2], Br[4][2];
  f32x4 acc[8][4] = {};

  // stage one half-tile (128 rows x 64 k): branchless, base + k-offset
  auto stgA = [&](int kof, int h, int bufel) {
    u16* dst = dstA0 + bufel + h * 8192;
    gld_lds16(aRow + (size_t)(h * 128) * KCAT + kof, dst);
    gld_lds16(aRow + (size_t)(h * 128 + 64) * KCAT + kof, dst + 4096);
  };
  auto stgB = [&](int kof, int h, int bufel) {
    u16* dst = dstB0 + bufel + h * 8192;
    gld_lds16(bRow + (size_t)(h * 128) * KCAT + kof, dst);
    gld_lds16(bRow + (size_t)(h * 128 + 64) * KCAT + kof, dst + 4096);
  };

  // prologue: tile0 full (buf0), then t1.B0,B1,A0 (buf1); gate tile0 (oldest 8 of 14)
  stgA(0, 0, 0);     stgA(0, 1, 0);
  stgB(0, 0, 0);     stgB(0, 1, 0);
  stgB(64, 0, BUF1); stgB(64, 1, BUF1);
  stgA(64, 0, BUF1);
  VMW6();
  BAR();

  for (int it = 0; it < NTILE / 2; ++it) {
    const int ka = it * 128;                       // tile a k-offset (elements)
    int c2 = ka + 128, c3 = ka + 192;              // prefetch tiles a+2, a+3
    if (c2 > KLAST) c2 = KLAST;                    // tail: re-stage junk (never read)
    if (c3 > KLAST) c3 = KLAST;
    // P1: Q00(a) | stage b.A1 -> buf1
    LDA(0, 0); LDB(0, 0);
    stgA(ka + 64, 1, BUF1);
    BAR(); MMQ(0, 0); BAR();
    // P2: Q01(a)
    LDB(0, 1);
    BAR(); MMQ(0, 1); BAR();
    // P3: Q11(a) | stage (a+2).B0,B1 -> buf0 (buf0.B read-done after P2)
    LDA(0, 1);
    stgB(c2, 0, 0); stgB(c2, 1, 0);
    BAR(); MMQ(1, 1); BAR();
    // P4: Q10(a) | stage (a+2).A0 -> buf0; gate tile b complete
    stgA(c2, 0, 0);
    BAR(); MMQ(1, 0);
    VMW6();
    BAR();
    // P5: Q00(b) | stage (a+2).A1 -> buf0
    LDA(BUF1, 0); LDB(BUF1, 0);
    stgA(c2, 1, 0);
    BAR(); MMQ(0, 0); BAR();
    // P6: Q01(b)
    LDB(BUF1, 1);
    BAR(); MMQ(0, 1); BAR();
    // P7: Q11(b) | stage (a+3).B0,B1 -> buf1 (buf1.B read-done after P6)
    LDA(BUF1, 1);
    stgB(c3, 0, BUF1); stgB(c3, 1, BUF1);
    BAR(); MMQ(1, 1); BAR();
    // P8: Q10(b) | stage (a+3).A0 -> buf1; gate tile a+2 complete
    stgA(c3, 0, BUF1);
    BAR(); MMQ(1, 0);
    VMW6();
    BAR();
  }

  // epilogue: bias + store (C/D mapping: row=...+lg*4+j, col=...+lr)
  float bv[4];
  #pragma unroll
  for (int n = 0; n < 4; ++n) bv[n] = bias[n0 + wn * 64 + n * 16 + lr];
  #pragma unroll
  for (int m = 0; m < 8; ++m) {
    const int row = m0 + wm * 128 + m * 16 + lg * 4;
    #pragma unroll
    for (int n = 0; n < 4; ++n) {
      const int col = n0 + wn * 64 + n * 16 + lr;
      float* op = out + (size_t)row * N_TOT + col;
      op[0 * (size_t)N_TOT] = acc[m][n][0] + bv[n];
      op[1 * (size_t)N_TOT] = acc[m][n][1] + bv[n];
      op[2 * (size_t)N_TOT] = acc[m][n][2] + bv[n];
      op[3 * (size_t)N_TOT] = acc[m][n][3] + bv[n];
    }
  }
}

extern "C" void kernel_launch(void* const* d_in, const int* in_sizes, int n_in,
                              void* d_out, int out_size, void* d_ws, size_t ws_size,
                              hipStream_t stream) {
  const float* x    = (const float*)d_in[0];
  const float* ss   = (const float*)d_in[1];
  const float* wq   = (const float*)d_in[2];
  const float* la   = (const float*)d_in[3];
  const float* lb   = (const float*)d_in[4];
  const float* wsp  = (const float*)d_in[5];
  const float* bias = (const float*)d_in[6];
  float* out = (float*)d_out;

  uint8_t* w = (uint8_t*)d_ws;
  u16* Ab  = (u16*)w;  w += (size_t)M_TOT * KCAT * 2;    // 130.0 MiB
  u16* Bb  = (u16*)w;  w += (size_t)N_TOT * KCAT * 2;    // 65.0 MiB
  u16* asb = (u16*)w;                                     // 0.25 MiB

  prep_b_k<<<33024, 256, 0, stream>>>(wq, wsp, lb, la, ss, Bb, asb);
  prep_x_k<<<M_TOT, 256, 0, stream>>>(x, ss, Ab);
  lora_t_mfma_k<<<M_TOT / 64, 256, 0, stream>>>(Ab, asb);

  hipFuncSetAttribute((const void*)gemm8_k,
                      hipFuncAttributeMaxDynamicSharedMemorySize, 131072);
  gemm8_k<<<dim3((N_TOT / 256) * (M_TOT / 256)), 512, 131072, stream>>>(
      Ab, Bb, bias, out);
}